// Round 10
// baseline (106.641 us; speedup 1.0000x reference)
//
#include <hip/hip_runtime.h>
#include <math.h>

#define N_PIX (4 * 512 * 1024)   // 2097152
#define C 19
#define HW (512 * 1024)
#define HW_SHIFT 19
#define IGNORE_INDEX 255
#define K_SEL 100000u
#define THRESH 0.7f

#define L0BINS 2048   // float bits [31:21]
#define L1BINS 2048   // bits [20:10]
#define L2BINS 1024   // bits [9:0]
#define NREP 4        // global histogram replicas (slow path only)
#define P1BLOCKS 2048 // = 8 blocks/CU * 256 CUs, 4 px/thread, co-resident
#define RFBLOCKS 512
#define RBLOCKS 512
#define NT 256

// ---------------------------------------------------------------------------
// Block-redundant scan of an NREP-replicated histogram (slow path only).
// Results in s_res[0]=bin, s_res[1]=k_rem. Ends with __syncthreads().
// ---------------------------------------------------------------------------
template <int NB>
__device__ __forceinline__ void scan_find(const unsigned* __restrict__ hist,
                                          unsigned k, unsigned* s_wsum,
                                          unsigned* s_res) {
  constexpr int BPT = NB / NT;
  int tid = threadIdx.x, lane = tid & 63, wd = tid >> 6;
  unsigned bins[BPT];
#pragma unroll
  for (int j = 0; j < BPT; j++) bins[j] = 0;
  for (int r = 0; r < NREP; r++) {
#pragma unroll
    for (int j = 0; j < BPT; j += 4) {
      uint4 h = *reinterpret_cast<const uint4*>(hist + r * NB + tid * BPT + j);
      bins[j] += h.x; bins[j + 1] += h.y;
      bins[j + 2] += h.z; bins[j + 3] += h.w;
    }
  }
  unsigned local = 0;
#pragma unroll
  for (int j = 0; j < BPT; j++) local += bins[j];
  unsigned v = local;
#pragma unroll
  for (int o = 1; o < 64; o <<= 1) {
    unsigned u = __shfl_up(v, o);
    if (lane >= o) v += u;
  }
  if (lane == 63) s_wsum[wd] = v;
  __syncthreads();
  unsigned wpre = 0;
  for (int w = 0; w < wd; w++) wpre += s_wsum[w];
  unsigned ex = v + wpre - local;
  if (ex < k && k <= ex + local) {  // exactly one thread
    unsigned c = ex;
#pragma unroll
    for (int j = 0; j < BPT; j++) {
      if (c < k && k <= c + bins[j]) {
        s_res[0] = (unsigned)(tid * BPT + j);
        s_res[1] = k - c;
      }
      c += bins[j];
    }
  }
  __syncthreads();
}

__device__ __forceinline__ void block_reduce2(float& s, float& c) {
  __shared__ float ls[4], lc[4];
#pragma unroll
  for (int o = 32; o > 0; o >>= 1) {
    s += __shfl_down(s, o);
    c += __shfl_down(c, o);
  }
  int wd = threadIdx.x >> 6;
  int lane = threadIdx.x & 63;
  if (lane == 0) { ls[wd] = s; lc[wd] = c; }
  __syncthreads();
  if (threadIdx.x == 0) {
    s = ls[0] + ls[1] + ls[2] + ls[3];
    c = lc[0] + lc[1] + lc[2] + lc[3];
  }
}

// ---------------------------------------------------------------------------
// pass1: software-pipelined class groups. Perf model from R5/R7/R9: throughput
// = waves/CU x outstanding-loads/wave (HW-capped ~4) x bytes/load. So: float4
// loads (1KB/wave-load), ONLY 8 float4 buffers live (2 rotating groups of 4,
// fully unrolled, static names -> no scratch), ~55-60 VGPR -> (256,8) = 32
// waves/CU co-resident (grid 2048 = 8 blocks/CU).
// Logits ~ N(0,1): single-pass exp without max-subtraction is fp32-safe.
// Also computes the fast-path reduce speculatively (thr=0.7): mp<=0.7 implies
// valid (invalid px have mp=1.0). No histogram here; slow path rebuilds it.
// ---------------------------------------------------------------------------
__global__ __launch_bounds__(NT, 8) void pass1_kernel(
    const float* __restrict__ pred, const int* __restrict__ tgt,
    float* __restrict__ maskprob, unsigned* __restrict__ c07,
    float* __restrict__ psumA, float* __restrict__ pcntA) {
  int tid = threadIdx.x;
  int p = blockIdx.x * (NT * 4) + tid * 4;
  int img = p >> HW_SHIFT;
  int hw = p & (HW - 1);
  const float* base = pred + img * (C * HW) + hw;
  int4 t4 = *reinterpret_cast<const int4*>(tgt + p);

  float s0 = 0.f, s1 = 0.f, s2 = 0.f, s3 = 0.f;
  float e0 = 0.f, e1 = 0.f, e2 = 0.f, e3 = 0.f;

#define LD(c) (*reinterpret_cast<const float4*>(base + (c) * HW))
#define CONS(v, c)                                                     \
  {                                                                    \
    float ex0 = __expf((v).x), ex1 = __expf((v).y);                    \
    float ex2 = __expf((v).z), ex3 = __expf((v).w);                    \
    s0 += ex0; s1 += ex1; s2 += ex2; s3 += ex3;                        \
    e0 = ((c) == t4.x) ? ex0 : e0;  /* c never equals 255 */           \
    e1 = ((c) == t4.y) ? ex1 : e1;                                     \
    e2 = ((c) == t4.z) ? ex2 : e2;                                     \
    e3 = ((c) == t4.w) ? ex3 : e3;                                     \
  }

  float4 a0, a1, a2, a3, b0, b1, b2, b3;
  // prologue: group 0 in flight
  a0 = LD(0); a1 = LD(1); a2 = LD(2); a3 = LD(3);
  // issue group 1, consume group 0
  b0 = LD(4); b1 = LD(5); b2 = LD(6); b3 = LD(7);
  CONS(a0, 0) CONS(a1, 1) CONS(a2, 2) CONS(a3, 3)
  // issue group 2, consume group 1
  a0 = LD(8); a1 = LD(9); a2 = LD(10); a3 = LD(11);
  CONS(b0, 4) CONS(b1, 5) CONS(b2, 6) CONS(b3, 7)
  // issue group 3, consume group 2
  b0 = LD(12); b1 = LD(13); b2 = LD(14); b3 = LD(15);
  CONS(a0, 8) CONS(a1, 9) CONS(a2, 10) CONS(a3, 11)
  // issue tail group (3 classes), consume group 3
  a0 = LD(16); a1 = LD(17); a2 = LD(18);
  CONS(b0, 12) CONS(b1, 13) CONS(b2, 14) CONS(b3, 15)
  // consume tail
  CONS(a0, 16) CONS(a1, 17) CONS(a2, 18)
#undef LD
#undef CONS

  bool va0 = t4.x != IGNORE_INDEX, va1 = t4.y != IGNORE_INDEX;
  bool va2 = t4.z != IGNORE_INDEX, va3 = t4.w != IGNORE_INDEX;
  float4 mp;
  mp.x = va0 ? e0 * __frcp_rn(s0) : 1.0f;
  mp.y = va1 ? e1 * __frcp_rn(s1) : 1.0f;
  mp.z = va2 ? e2 * __frcp_rn(s2) : 1.0f;
  mp.w = va3 ? e3 * __frcp_rn(s3) : 1.0f;
  *reinterpret_cast<float4*>(maskprob + p) = mp;

  // speculative fast-path masked sum (thr = 0.7)
  float s = 0.f, cn = 0.f;
  if (mp.x <= THRESH) { s -= __logf(mp.x); cn += 1.f; }
  if (mp.y <= THRESH) { s -= __logf(mp.y); cn += 1.f; }
  if (mp.z <= THRESH) { s -= __logf(mp.z); cn += 1.f; }
  if (mp.w <= THRESH) { s -= __logf(mp.w); cn += 1.f; }
  block_reduce2(s, cn);
  if (tid == 0) {
    psumA[blockIdx.x] = s;
    pcntA[blockIdx.x] = cn;
    if (cn > 0.f) atomicAdd(c07, (unsigned)cn);   // cn is an exact small int
  }
}

// ---------------------------------------------------------------------------
// hist0 (slow path only): top-11-bit histogram of maskprob.
// ---------------------------------------------------------------------------
__global__ __launch_bounds__(NT) void hist0_kernel(
    const float* __restrict__ maskprob, const unsigned* __restrict__ c07,
    unsigned* __restrict__ hist0) {
  if (*c07 >= K_SEL) return;   // fast path: threshold == 0.7
  __shared__ unsigned lh[L0BINS];
  int tid = threadIdx.x;
  for (int i = tid; i < L0BINS; i += NT) lh[i] = 0;
  __syncthreads();
#pragma unroll
  for (int it = 0; it < 4; it++) {
    int q = (it * RFBLOCKS + blockIdx.x) * NT + tid;
    float4 m = reinterpret_cast<const float4*>(maskprob)[q];
    atomicAdd(&lh[__float_as_uint(m.x) >> 21], 1u);
    atomicAdd(&lh[__float_as_uint(m.y) >> 21], 1u);
    atomicAdd(&lh[__float_as_uint(m.z) >> 21], 1u);
    atomicAdd(&lh[__float_as_uint(m.w) >> 21], 1u);
  }
  __syncthreads();
  unsigned rep = blockIdx.x & (NREP - 1);
  for (int i = tid; i < L0BINS; i += NT)
    if (lh[i]) atomicAdd(&hist0[rep * L0BINS + i], lh[i]);
}

// ---------------------------------------------------------------------------
// refine1 (slow path only): scan hist0 (k=K_SEL) -> ctrl[0..1]; histogram
// bits[20:10] of prefix-matching elements into hist1.
// ---------------------------------------------------------------------------
__global__ __launch_bounds__(NT) void refine1_kernel(
    const float* __restrict__ maskprob, const unsigned* __restrict__ c07,
    const unsigned* __restrict__ hist0, unsigned* __restrict__ hist1,
    unsigned* __restrict__ ctrl) {
  if (*c07 >= K_SEL) return;
  __shared__ unsigned lh[L1BINS];
  __shared__ unsigned s_wsum[4];
  __shared__ unsigned s_res[2];
  int tid = threadIdx.x;

  scan_find<L0BINS>(hist0, K_SEL, s_wsum, s_res);
  unsigned pre0 = s_res[0];
  if (tid == 0) { ctrl[0] = pre0; ctrl[1] = s_res[1]; }

  for (int i = tid; i < L1BINS; i += NT) lh[i] = 0;
  __syncthreads();
#pragma unroll
  for (int it = 0; it < 4; it++) {
    int q = (it * RFBLOCKS + blockIdx.x) * NT + tid;
    float4 m = reinterpret_cast<const float4*>(maskprob)[q];
    unsigned bx = __float_as_uint(m.x), by = __float_as_uint(m.y);
    unsigned bz = __float_as_uint(m.z), bw = __float_as_uint(m.w);
    if ((bx >> 21) == pre0) atomicAdd(&lh[(bx >> 10) & (L1BINS - 1)], 1u);
    if ((by >> 21) == pre0) atomicAdd(&lh[(by >> 10) & (L1BINS - 1)], 1u);
    if ((bz >> 21) == pre0) atomicAdd(&lh[(bz >> 10) & (L1BINS - 1)], 1u);
    if ((bw >> 21) == pre0) atomicAdd(&lh[(bw >> 10) & (L1BINS - 1)], 1u);
  }
  __syncthreads();
  unsigned rep = blockIdx.x & (NREP - 1);
  for (int i = tid; i < L1BINS; i += NT)
    if (lh[i]) atomicAdd(&hist1[rep * L1BINS + i], lh[i]);
}

// ---------------------------------------------------------------------------
// refine2 (slow path only): scan hist1 (k=ctrl[1]) -> ctrl[2..3]; histogram
// bits[9:0] into hist2.
// ---------------------------------------------------------------------------
__global__ __launch_bounds__(NT) void refine2_kernel(
    const float* __restrict__ maskprob, const unsigned* __restrict__ c07,
    const unsigned* __restrict__ hist1, unsigned* __restrict__ hist2,
    unsigned* __restrict__ ctrl) {
  if (*c07 >= K_SEL) return;
  __shared__ unsigned lh[L2BINS];
  __shared__ unsigned s_wsum[4];
  __shared__ unsigned s_res[2];
  int tid = threadIdx.x;

  unsigned pre0 = ctrl[0];
  unsigned krem0 = ctrl[1];
  scan_find<L1BINS>(hist1, krem0, s_wsum, s_res);
  unsigned pre1 = (pre0 << 11) | s_res[0];
  if (tid == 0) { ctrl[2] = pre1; ctrl[3] = s_res[1]; }

  for (int i = tid; i < L2BINS; i += NT) lh[i] = 0;
  __syncthreads();
#pragma unroll
  for (int it = 0; it < 4; it++) {
    int q = (it * RFBLOCKS + blockIdx.x) * NT + tid;
    float4 m = reinterpret_cast<const float4*>(maskprob)[q];
    unsigned bx = __float_as_uint(m.x), by = __float_as_uint(m.y);
    unsigned bz = __float_as_uint(m.z), bw = __float_as_uint(m.w);
    if ((bx >> 10) == pre1) atomicAdd(&lh[bx & (L2BINS - 1)], 1u);
    if ((by >> 10) == pre1) atomicAdd(&lh[by & (L2BINS - 1)], 1u);
    if ((bz >> 10) == pre1) atomicAdd(&lh[bz & (L2BINS - 1)], 1u);
    if ((bw >> 10) == pre1) atomicAdd(&lh[bw & (L2BINS - 1)], 1u);
  }
  __syncthreads();
  unsigned rep = blockIdx.x & (NREP - 1);
  for (int i = tid; i < L2BINS; i += NT)
    if (lh[i]) atomicAdd(&hist2[rep * L2BINS + i], lh[i]);
}

// ---------------------------------------------------------------------------
// reduce: FAST PATH (c07 >= K): block 0 combines pass1's speculative partials
// (thr == 0.7 exactly) — no data re-read. SLOW PATH: scan hist2 -> exact kth
// threshold, full masked re-read, ticket finalize. Deterministic both ways.
// ---------------------------------------------------------------------------
__global__ __launch_bounds__(NT) void reduce_kernel(
    const float* __restrict__ maskprob, const int* __restrict__ tgt,
    const unsigned* __restrict__ c07, const unsigned* __restrict__ hist2,
    const unsigned* __restrict__ ctrl, const float* __restrict__ psumA,
    const float* __restrict__ pcntA, float* __restrict__ psum,
    float* __restrict__ pcnt, unsigned* __restrict__ ticket,
    float* __restrict__ out) {
  int tid = threadIdx.x;

  if (*c07 >= K_SEL) {
    if (blockIdx.x == 0) {
      float fs = 0.f, fc = 0.f;
      for (int i = tid; i < P1BLOCKS; i += NT) {
        fs += psumA[i];
        fc += pcntA[i];
      }
      block_reduce2(fs, fc);
      if (tid == 0) out[0] = fs / fmaxf(fc, 1.0f);
    }
    return;
  }

  // ---- slow path ----
  __shared__ unsigned s_wsum[4];
  __shared__ unsigned s_res[2];
  __shared__ bool s_last;
  unsigned pre1 = ctrl[2];
  unsigned krem1 = ctrl[3];
  scan_find<L2BINS>(hist2, krem1, s_wsum, s_res);
  float thr = fmaxf(__uint_as_float((pre1 << 10) | s_res[0]), THRESH);

  float s = 0.f, cn = 0.f;
#pragma unroll
  for (int it = 0; it < 4; it++) {
    int q = (it * RBLOCKS + blockIdx.x) * NT + tid;
    float4 m = reinterpret_cast<const float4*>(maskprob)[q];
    int4 t4 = reinterpret_cast<const int4*>(tgt)[q];
    if (t4.x != IGNORE_INDEX && m.x <= thr) { s -= __logf(m.x); cn += 1.f; }
    if (t4.y != IGNORE_INDEX && m.y <= thr) { s -= __logf(m.y); cn += 1.f; }
    if (t4.z != IGNORE_INDEX && m.z <= thr) { s -= __logf(m.z); cn += 1.f; }
    if (t4.w != IGNORE_INDEX && m.w <= thr) { s -= __logf(m.w); cn += 1.f; }
  }
  block_reduce2(s, cn);
  if (tid == 0) {
    psum[blockIdx.x] = s;
    pcnt[blockIdx.x] = cn;
    __threadfence();
    s_last = (atomicAdd(ticket, 1u) == RBLOCKS - 1);
  }
  __syncthreads();
  if (s_last) {
    __threadfence();
    volatile const float* vs = psum;
    volatile const float* vc = pcnt;
    float fs = 0.f, fc = 0.f;
    for (int i = tid; i < RBLOCKS; i += NT) {
      fs += vs[i];
      fc += vc[i];
    }
    block_reduce2(fs, fc);
    if (tid == 0) out[0] = fs / fmaxf(fc, 1.0f);
  }
}

// ---------------------------------------------------------------------------
extern "C" void kernel_launch(void* const* d_in, const int* in_sizes, int n_in,
                              void* d_out, int out_size, void* d_ws,
                              size_t ws_size, hipStream_t stream) {
  const float* pred = (const float*)d_in[0];
  const int* tgt = (const int*)d_in[1];
  float* out = (float*)d_out;

  float* maskprob = (float*)d_ws;                    // 8 MB
  unsigned* hist0 = (unsigned*)(maskprob + N_PIX);   // NREP*2048
  unsigned* hist1 = hist0 + NREP * L0BINS;           // NREP*2048
  unsigned* hist2 = hist1 + NREP * L1BINS;           // NREP*1024
  unsigned* ctrl = hist2 + NREP * L2BINS;            // 16 words
  unsigned* ticket = ctrl + 8;
  unsigned* c07 = ctrl + 9;
  float* psum = (float*)(ctrl + 16);                 // RBLOCKS
  float* pcnt = psum + RBLOCKS;                      // RBLOCKS
  float* psumA = pcnt + RBLOCKS;                     // P1BLOCKS
  float* pcntA = psumA + P1BLOCKS;                   // P1BLOCKS
  size_t zbytes = (char*)(ctrl + 16) - (char*)hist0;

  hipMemsetAsync(hist0, 0, zbytes, stream);
  pass1_kernel<<<P1BLOCKS, NT, 0, stream>>>(pred, tgt, maskprob, c07, psumA,
                                            pcntA);
  hist0_kernel<<<RFBLOCKS, NT, 0, stream>>>(maskprob, c07, hist0);
  refine1_kernel<<<RFBLOCKS, NT, 0, stream>>>(maskprob, c07, hist0, hist1, ctrl);
  refine2_kernel<<<RFBLOCKS, NT, 0, stream>>>(maskprob, c07, hist1, hist2, ctrl);
  reduce_kernel<<<RBLOCKS, NT, 0, stream>>>(maskprob, tgt, c07, hist2, ctrl,
                                            psumA, pcntA, psum, pcnt, ticket,
                                            out);
}

// Round 11
// 55.512 us; speedup vs baseline: 1.9210x; 1.9210x over previous
//
#include <hip/hip_runtime.h>
#include <math.h>

#define N_PIX (4 * 512 * 1024)   // 2097152
#define C 19
#define HW (512 * 1024)
#define HW_SHIFT 19
#define IGNORE_INDEX 255
#define K_SEL 100000u
#define THRESH 0.7f

#define L0BINS 2048   // float bits [31:21]
#define L1BINS 2048   // bits [20:10]
#define L2BINS 1024   // bits [9:0]
#define NREP 4        // global histogram replicas (slow path only)
#define P1BLOCKS 1024
#define RFBLOCKS 512
#define RBLOCKS 512
#define NT 256

// ---------------------------------------------------------------------------
// Block-redundant scan of an NREP-replicated histogram (slow path only).
// Results in s_res[0]=bin, s_res[1]=k_rem. Ends with __syncthreads().
// ---------------------------------------------------------------------------
template <int NB>
__device__ __forceinline__ void scan_find(const unsigned* __restrict__ hist,
                                          unsigned k, unsigned* s_wsum,
                                          unsigned* s_res) {
  constexpr int BPT = NB / NT;
  int tid = threadIdx.x, lane = tid & 63, wd = tid >> 6;
  unsigned bins[BPT];
#pragma unroll
  for (int j = 0; j < BPT; j++) bins[j] = 0;
  for (int r = 0; r < NREP; r++) {
#pragma unroll
    for (int j = 0; j < BPT; j += 4) {
      uint4 h = *reinterpret_cast<const uint4*>(hist + r * NB + tid * BPT + j);
      bins[j] += h.x; bins[j + 1] += h.y;
      bins[j + 2] += h.z; bins[j + 3] += h.w;
    }
  }
  unsigned local = 0;
#pragma unroll
  for (int j = 0; j < BPT; j++) local += bins[j];
  unsigned v = local;
#pragma unroll
  for (int o = 1; o < 64; o <<= 1) {
    unsigned u = __shfl_up(v, o);
    if (lane >= o) v += u;
  }
  if (lane == 63) s_wsum[wd] = v;
  __syncthreads();
  unsigned wpre = 0;
  for (int w = 0; w < wd; w++) wpre += s_wsum[w];
  unsigned ex = v + wpre - local;
  if (ex < k && k <= ex + local) {  // exactly one thread
    unsigned c = ex;
#pragma unroll
    for (int j = 0; j < BPT; j++) {
      if (c < k && k <= c + bins[j]) {
        s_res[0] = (unsigned)(tid * BPT + j);
        s_res[1] = k - c;
      }
      c += bins[j];
    }
  }
  __syncthreads();
}

__device__ __forceinline__ void block_reduce2(float& s, float& c) {
  __shared__ float ls[4], lc[4];
#pragma unroll
  for (int o = 32; o > 0; o >>= 1) {
    s += __shfl_down(s, o);
    c += __shfl_down(c, o);
  }
  int wd = threadIdx.x >> 6;
  int lane = threadIdx.x & 63;
  if (lane == 0) { ls[wd] = s; lc[wd] = c; }
  __syncthreads();
  if (threadIdx.x == 0) {
    s = ls[0] + ls[1] + ls[2] + ls[3];
    c = lc[0] + lc[1] + lc[2] + lc[3];
  }
}

// ---------------------------------------------------------------------------
// pass1 (STORE-FREE): R5's proven memory structure — (256,4) => 128-VGPR cap,
// all 19 float4 streams live (compiler schedules them wide; R9/R10 proved
// hand-pipelining + tight caps collapse to 2 in-flight), 4 px/thread x 2
// iters. NO maskprob store, NO LDS histogram: only per-block partials of the
// speculative fast-path sum (thr=0.7). R10 counters showed pass1's stores
// drag ~90MB of write-side traffic vs 8MB stored — this kernel is pure-read
// 167MB + 16KB partials. Slow path (never taken on bench data) recomputes
// everything from pred via the gated kernels below.
// mp<=0.7 implies valid (invalid px have mp=1.0), so cnt == count(valid&kept).
// ---------------------------------------------------------------------------
__global__ __launch_bounds__(NT, 4) void pass1_kernel(
    const float* __restrict__ pred, const int* __restrict__ tgt,
    unsigned* __restrict__ c07, float* __restrict__ psumA,
    float* __restrict__ pcntA) {
  int tid = threadIdx.x;
  float s = 0.f, cn = 0.f;

#pragma unroll
  for (int iter = 0; iter < 2; iter++) {
    int p = ((iter * P1BLOCKS + blockIdx.x) * NT + tid) * 4;
    int img = p >> HW_SHIFT;
    int hw = p & (HW - 1);
    const float* base = pred + img * (C * HW) + hw;
    int4 t4 = *reinterpret_cast<const int4*>(tgt + p);

    // logits ~ N(0,1): single-pass exp without max-subtraction is fp32-safe.
    float s0 = 0.f, s1 = 0.f, s2 = 0.f, s3 = 0.f;
    float e0 = 0.f, e1 = 0.f, e2 = 0.f, e3 = 0.f;
#pragma unroll
    for (int c = 0; c < C; c++) {
      float4 x = *reinterpret_cast<const float4*>(base + c * HW);
      float ex0 = __expf(x.x), ex1 = __expf(x.y);
      float ex2 = __expf(x.z), ex3 = __expf(x.w);
      s0 += ex0; s1 += ex1; s2 += ex2; s3 += ex3;
      e0 = (c == t4.x) ? ex0 : e0;   // c never equals 255; static indexing
      e1 = (c == t4.y) ? ex1 : e1;
      e2 = (c == t4.z) ? ex2 : e2;
      e3 = (c == t4.w) ? ex3 : e3;
    }
    bool va0 = t4.x != IGNORE_INDEX, va1 = t4.y != IGNORE_INDEX;
    bool va2 = t4.z != IGNORE_INDEX, va3 = t4.w != IGNORE_INDEX;
    float mp0 = va0 ? e0 * __frcp_rn(s0) : 1.0f;
    float mp1 = va1 ? e1 * __frcp_rn(s1) : 1.0f;
    float mp2 = va2 ? e2 * __frcp_rn(s2) : 1.0f;
    float mp3 = va3 ? e3 * __frcp_rn(s3) : 1.0f;

    if (mp0 <= THRESH) { s -= __logf(mp0); cn += 1.f; }
    if (mp1 <= THRESH) { s -= __logf(mp1); cn += 1.f; }
    if (mp2 <= THRESH) { s -= __logf(mp2); cn += 1.f; }
    if (mp3 <= THRESH) { s -= __logf(mp3); cn += 1.f; }
  }

  block_reduce2(s, cn);
  if (tid == 0) {
    psumA[blockIdx.x] = s;
    pcntA[blockIdx.x] = cn;
    if (cn > 0.f) atomicAdd(c07, (unsigned)cn);   // cn is an exact small int
  }
}

// ---------------------------------------------------------------------------
// pass1_full (SLOW PATH ONLY, gated): recompute mask_prob from pred, write
// maskprob + top-11-bit LDS histogram. This is R8's verified pass1. Never
// runs when c07 >= K_SEL.
// ---------------------------------------------------------------------------
__global__ __launch_bounds__(NT, 4) void pass1_full_kernel(
    const float* __restrict__ pred, const int* __restrict__ tgt,
    const unsigned* __restrict__ c07, float* __restrict__ maskprob,
    unsigned* __restrict__ hist0) {
  if (*c07 >= K_SEL) return;
  __shared__ unsigned lh[4 * L0BINS];   // 32 KB
  int tid = threadIdx.x;
  int wid = tid >> 6;
  for (int i = tid; i < 4 * L0BINS; i += NT) lh[i] = 0;
  __syncthreads();

#pragma unroll
  for (int iter = 0; iter < 2; iter++) {
    int p = ((iter * P1BLOCKS + blockIdx.x) * NT + tid) * 4;
    int img = p >> HW_SHIFT;
    int hw = p & (HW - 1);
    const float* base = pred + img * (C * HW) + hw;
    int4 t4 = *reinterpret_cast<const int4*>(tgt + p);

    float s0 = 0.f, s1 = 0.f, s2 = 0.f, s3 = 0.f;
    float e0 = 0.f, e1 = 0.f, e2 = 0.f, e3 = 0.f;
#pragma unroll
    for (int c = 0; c < C; c++) {
      float4 x = *reinterpret_cast<const float4*>(base + c * HW);
      float ex0 = __expf(x.x), ex1 = __expf(x.y);
      float ex2 = __expf(x.z), ex3 = __expf(x.w);
      s0 += ex0; s1 += ex1; s2 += ex2; s3 += ex3;
      e0 = (c == t4.x) ? ex0 : e0;
      e1 = (c == t4.y) ? ex1 : e1;
      e2 = (c == t4.z) ? ex2 : e2;
      e3 = (c == t4.w) ? ex3 : e3;
    }
    bool va0 = t4.x != IGNORE_INDEX, va1 = t4.y != IGNORE_INDEX;
    bool va2 = t4.z != IGNORE_INDEX, va3 = t4.w != IGNORE_INDEX;
    float4 mp;
    mp.x = va0 ? e0 * __frcp_rn(s0) : 1.0f;
    mp.y = va1 ? e1 * __frcp_rn(s1) : 1.0f;
    mp.z = va2 ? e2 * __frcp_rn(s2) : 1.0f;
    mp.w = va3 ? e3 * __frcp_rn(s3) : 1.0f;
    *reinterpret_cast<float4*>(maskprob + p) = mp;

    atomicAdd(&lh[(wid << 11) | (__float_as_uint(mp.x) >> 21)], 1u);
    atomicAdd(&lh[(wid << 11) | (__float_as_uint(mp.y) >> 21)], 1u);
    atomicAdd(&lh[(wid << 11) | (__float_as_uint(mp.z) >> 21)], 1u);
    atomicAdd(&lh[(wid << 11) | (__float_as_uint(mp.w) >> 21)], 1u);
  }
  __syncthreads();
  unsigned rep = blockIdx.x & (NREP - 1);
  for (int i = tid; i < L0BINS; i += NT) {
    unsigned tot = lh[i] + lh[L0BINS + i] + lh[2 * L0BINS + i] +
                   lh[3 * L0BINS + i];
    if (tot) atomicAdd(&hist0[rep * L0BINS + i], tot);
  }
}

// ---------------------------------------------------------------------------
// refine1 (slow path only): scan hist0 (k=K_SEL) -> ctrl[0..1]; histogram
// bits[20:10] of prefix-matching elements into hist1.
// ---------------------------------------------------------------------------
__global__ __launch_bounds__(NT) void refine1_kernel(
    const float* __restrict__ maskprob, const unsigned* __restrict__ c07,
    const unsigned* __restrict__ hist0, unsigned* __restrict__ hist1,
    unsigned* __restrict__ ctrl) {
  if (*c07 >= K_SEL) return;
  __shared__ unsigned lh[L1BINS];
  __shared__ unsigned s_wsum[4];
  __shared__ unsigned s_res[2];
  int tid = threadIdx.x;

  scan_find<L0BINS>(hist0, K_SEL, s_wsum, s_res);
  unsigned pre0 = s_res[0];
  if (tid == 0) { ctrl[0] = pre0; ctrl[1] = s_res[1]; }

  for (int i = tid; i < L1BINS; i += NT) lh[i] = 0;
  __syncthreads();
#pragma unroll
  for (int it = 0; it < 4; it++) {
    int q = (it * RFBLOCKS + blockIdx.x) * NT + tid;
    float4 m = reinterpret_cast<const float4*>(maskprob)[q];
    unsigned bx = __float_as_uint(m.x), by = __float_as_uint(m.y);
    unsigned bz = __float_as_uint(m.z), bw = __float_as_uint(m.w);
    if ((bx >> 21) == pre0) atomicAdd(&lh[(bx >> 10) & (L1BINS - 1)], 1u);
    if ((by >> 21) == pre0) atomicAdd(&lh[(by >> 10) & (L1BINS - 1)], 1u);
    if ((bz >> 21) == pre0) atomicAdd(&lh[(bz >> 10) & (L1BINS - 1)], 1u);
    if ((bw >> 21) == pre0) atomicAdd(&lh[(bw >> 10) & (L1BINS - 1)], 1u);
  }
  __syncthreads();
  unsigned rep = blockIdx.x & (NREP - 1);
  for (int i = tid; i < L1BINS; i += NT)
    if (lh[i]) atomicAdd(&hist1[rep * L1BINS + i], lh[i]);
}

// ---------------------------------------------------------------------------
// refine2 (slow path only): scan hist1 (k=ctrl[1]) -> ctrl[2..3]; histogram
// bits[9:0] into hist2.
// ---------------------------------------------------------------------------
__global__ __launch_bounds__(NT) void refine2_kernel(
    const float* __restrict__ maskprob, const unsigned* __restrict__ c07,
    const unsigned* __restrict__ hist1, unsigned* __restrict__ hist2,
    unsigned* __restrict__ ctrl) {
  if (*c07 >= K_SEL) return;
  __shared__ unsigned lh[L2BINS];
  __shared__ unsigned s_wsum[4];
  __shared__ unsigned s_res[2];
  int tid = threadIdx.x;

  unsigned pre0 = ctrl[0];
  unsigned krem0 = ctrl[1];
  scan_find<L1BINS>(hist1, krem0, s_wsum, s_res);
  unsigned pre1 = (pre0 << 11) | s_res[0];
  if (tid == 0) { ctrl[2] = pre1; ctrl[3] = s_res[1]; }

  for (int i = tid; i < L2BINS; i += NT) lh[i] = 0;
  __syncthreads();
#pragma unroll
  for (int it = 0; it < 4; it++) {
    int q = (it * RFBLOCKS + blockIdx.x) * NT + tid;
    float4 m = reinterpret_cast<const float4*>(maskprob)[q];
    unsigned bx = __float_as_uint(m.x), by = __float_as_uint(m.y);
    unsigned bz = __float_as_uint(m.z), bw = __float_as_uint(m.w);
    if ((bx >> 10) == pre1) atomicAdd(&lh[bx & (L2BINS - 1)], 1u);
    if ((by >> 10) == pre1) atomicAdd(&lh[by & (L2BINS - 1)], 1u);
    if ((bz >> 10) == pre1) atomicAdd(&lh[bz & (L2BINS - 1)], 1u);
    if ((bw >> 10) == pre1) atomicAdd(&lh[bw & (L2BINS - 1)], 1u);
  }
  __syncthreads();
  unsigned rep = blockIdx.x & (NREP - 1);
  for (int i = tid; i < L2BINS; i += NT)
    if (lh[i]) atomicAdd(&hist2[rep * L2BINS + i], lh[i]);
}

// ---------------------------------------------------------------------------
// reduce: FAST PATH (c07 >= K): block 0 combines pass1's partials (thr == 0.7
// exactly) — no bulk data read at all. SLOW PATH: scan hist2 -> exact kth
// threshold, masked re-read of maskprob+tgt, ticket finalize. Deterministic.
// ---------------------------------------------------------------------------
__global__ __launch_bounds__(NT) void reduce_kernel(
    const float* __restrict__ maskprob, const int* __restrict__ tgt,
    const unsigned* __restrict__ c07, const unsigned* __restrict__ hist2,
    const unsigned* __restrict__ ctrl, const float* __restrict__ psumA,
    const float* __restrict__ pcntA, float* __restrict__ psum,
    float* __restrict__ pcnt, unsigned* __restrict__ ticket,
    float* __restrict__ out) {
  int tid = threadIdx.x;

  if (*c07 >= K_SEL) {
    if (blockIdx.x == 0) {
      float fs = 0.f, fc = 0.f;
      for (int i = tid; i < P1BLOCKS; i += NT) {
        fs += psumA[i];
        fc += pcntA[i];
      }
      block_reduce2(fs, fc);
      if (tid == 0) out[0] = fs / fmaxf(fc, 1.0f);
    }
    return;
  }

  // ---- slow path ----
  __shared__ unsigned s_wsum[4];
  __shared__ unsigned s_res[2];
  __shared__ bool s_last;
  unsigned pre1 = ctrl[2];
  unsigned krem1 = ctrl[3];
  scan_find<L2BINS>(hist2, krem1, s_wsum, s_res);
  float thr = fmaxf(__uint_as_float((pre1 << 10) | s_res[0]), THRESH);

  float s = 0.f, cn = 0.f;
#pragma unroll
  for (int it = 0; it < 4; it++) {
    int q = (it * RBLOCKS + blockIdx.x) * NT + tid;
    float4 m = reinterpret_cast<const float4*>(maskprob)[q];
    int4 t4 = reinterpret_cast<const int4*>(tgt)[q];
    if (t4.x != IGNORE_INDEX && m.x <= thr) { s -= __logf(m.x); cn += 1.f; }
    if (t4.y != IGNORE_INDEX && m.y <= thr) { s -= __logf(m.y); cn += 1.f; }
    if (t4.z != IGNORE_INDEX && m.z <= thr) { s -= __logf(m.z); cn += 1.f; }
    if (t4.w != IGNORE_INDEX && m.w <= thr) { s -= __logf(m.w); cn += 1.f; }
  }
  block_reduce2(s, cn);
  if (tid == 0) {
    psum[blockIdx.x] = s;
    pcnt[blockIdx.x] = cn;
    __threadfence();
    s_last = (atomicAdd(ticket, 1u) == RBLOCKS - 1);
  }
  __syncthreads();
  if (s_last) {
    __threadfence();
    volatile const float* vs = psum;
    volatile const float* vc = pcnt;
    float fs = 0.f, fc = 0.f;
    for (int i = tid; i < RBLOCKS; i += NT) {
      fs += vs[i];
      fc += vc[i];
    }
    block_reduce2(fs, fc);
    if (tid == 0) out[0] = fs / fmaxf(fc, 1.0f);
  }
}

// ---------------------------------------------------------------------------
extern "C" void kernel_launch(void* const* d_in, const int* in_sizes, int n_in,
                              void* d_out, int out_size, void* d_ws,
                              size_t ws_size, hipStream_t stream) {
  const float* pred = (const float*)d_in[0];
  const int* tgt = (const int*)d_in[1];
  float* out = (float*)d_out;

  float* maskprob = (float*)d_ws;                    // 8 MB (slow path only)
  unsigned* hist0 = (unsigned*)(maskprob + N_PIX);   // NREP*2048
  unsigned* hist1 = hist0 + NREP * L0BINS;           // NREP*2048
  unsigned* hist2 = hist1 + NREP * L1BINS;           // NREP*1024
  unsigned* ctrl = hist2 + NREP * L2BINS;            // 16 words
  unsigned* ticket = ctrl + 8;
  unsigned* c07 = ctrl + 9;
  float* psum = (float*)(ctrl + 16);                 // RBLOCKS
  float* pcnt = psum + RBLOCKS;                      // RBLOCKS
  float* psumA = pcnt + RBLOCKS;                     // P1BLOCKS
  float* pcntA = psumA + P1BLOCKS;                   // P1BLOCKS
  size_t zbytes = (char*)(ctrl + 16) - (char*)hist0;

  hipMemsetAsync(hist0, 0, zbytes, stream);
  pass1_kernel<<<P1BLOCKS, NT, 0, stream>>>(pred, tgt, c07, psumA, pcntA);
  pass1_full_kernel<<<P1BLOCKS, NT, 0, stream>>>(pred, tgt, c07, maskprob,
                                                 hist0);
  refine1_kernel<<<RFBLOCKS, NT, 0, stream>>>(maskprob, c07, hist0, hist1, ctrl);
  refine2_kernel<<<RFBLOCKS, NT, 0, stream>>>(maskprob, c07, hist1, hist2, ctrl);
  reduce_kernel<<<RBLOCKS, NT, 0, stream>>>(maskprob, tgt, c07, hist2, ctrl,
                                            psumA, pcntA, psum, pcnt, ticket,
                                            out);
}

// Round 12
// 54.071 us; speedup vs baseline: 1.9722x; 1.0267x over previous
//
#include <hip/hip_runtime.h>
#include <math.h>

#define N_PIX (4 * 512 * 1024)   // 2097152
#define C 19
#define HW (512 * 1024)
#define HW_SHIFT 19
#define IGNORE_INDEX 255
#define K_SEL 100000u
#define THRESH 0.7f

#define L0BINS 2048   // float bits [31:21]
#define L1BINS 2048   // bits [20:10]
#define L2BINS 1024   // bits [9:0]
#define NREP 4        // global histogram replicas (slow path only)
#define P1BLOCKS 2048 // 1024 px per block
#define FPBLOCKS 1024 // slow-path full pass grid
#define RFBLOCKS 512
#define RBLOCKS 512
#define NT 256

// ---------------------------------------------------------------------------
// Block-redundant scan of an NREP-replicated histogram (slow path only).
// Results in s_res[0]=bin, s_res[1]=k_rem. Ends with __syncthreads().
// ---------------------------------------------------------------------------
template <int NB>
__device__ __forceinline__ void scan_find(const unsigned* __restrict__ hist,
                                          unsigned k, unsigned* s_wsum,
                                          unsigned* s_res) {
  constexpr int BPT = NB / NT;
  int tid = threadIdx.x, lane = tid & 63, wd = tid >> 6;
  unsigned bins[BPT];
#pragma unroll
  for (int j = 0; j < BPT; j++) bins[j] = 0;
  for (int r = 0; r < NREP; r++) {
#pragma unroll
    for (int j = 0; j < BPT; j += 4) {
      uint4 h = *reinterpret_cast<const uint4*>(hist + r * NB + tid * BPT + j);
      bins[j] += h.x; bins[j + 1] += h.y;
      bins[j + 2] += h.z; bins[j + 3] += h.w;
    }
  }
  unsigned local = 0;
#pragma unroll
  for (int j = 0; j < BPT; j++) local += bins[j];
  unsigned v = local;
#pragma unroll
  for (int o = 1; o < 64; o <<= 1) {
    unsigned u = __shfl_up(v, o);
    if (lane >= o) v += u;
  }
  if (lane == 63) s_wsum[wd] = v;
  __syncthreads();
  unsigned wpre = 0;
  for (int w = 0; w < wd; w++) wpre += s_wsum[w];
  unsigned ex = v + wpre - local;
  if (ex < k && k <= ex + local) {  // exactly one thread
    unsigned c = ex;
#pragma unroll
    for (int j = 0; j < BPT; j++) {
      if (c < k && k <= c + bins[j]) {
        s_res[0] = (unsigned)(tid * BPT + j);
        s_res[1] = k - c;
      }
      c += bins[j];
    }
  }
  __syncthreads();
}

__device__ __forceinline__ void block_reduce2(float& s, float& c) {
  __shared__ float ls[4], lc[4];
#pragma unroll
  for (int o = 32; o > 0; o >>= 1) {
    s += __shfl_down(s, o);
    c += __shfl_down(c, o);
  }
  int wd = threadIdx.x >> 6;
  int lane = threadIdx.x & 63;
  if (lane == 0) { ls[wd] = s; lc[wd] = c; }
  __syncthreads();
  if (threadIdx.x == 0) {
    s = ls[0] + ls[1] + ls[2] + ls[3];
    c = lc[0] + lc[1] + lc[2] + lc[3];
  }
}

// ---------------------------------------------------------------------------
// pass1: ASYNC-STAGED. Each wave issues all 19 class loads direct-to-LDS via
// global_load_lds (fire-and-forget: NO dest register, so the regalloc CANNOT
// collapse the pipeline — R9/R10 proved register-destination loads get sunk
// to ~2 in flight). 19 KB/wave in flight; (256,2) + 76 KB LDS -> 2 blocks/CU
// -> 152 KB in flight per CU (vs ~12 KB before). Consumption gated by
// explicit s_waitcnt vmcnt(18-c) + sched_barrier(0) (rule #18). t4 is pinned
// complete BEFORE staging so the vmcnt ledger counts only stage loads.
// Store-free fast path: per-block partials of the thr=0.7 sum (proven R11).
// mp<=0.7 implies valid (invalid px have mp=1.0).
// ---------------------------------------------------------------------------
__global__ __launch_bounds__(NT, 2) void pass1_kernel(
    const float* __restrict__ pred, const int* __restrict__ tgt,
    unsigned* __restrict__ c07, float* __restrict__ psumA,
    float* __restrict__ pcntA) {
  __shared__ float stage[4][C][256];   // 76 KB: [wave][class][256 floats]
  int tid = threadIdx.x;
  int w = tid >> 6;
  int lane = tid & 63;
  int p = blockIdx.x * (NT * 4) + tid * 4;
  int img = p >> HW_SHIFT;
  int hw = p & (HW - 1);
  const float* base = pred + img * (C * HW) + hw;

  int4 t4 = *reinterpret_cast<const int4*>(tgt + p);
  // Pin t4 materialized NOW (compiler inserts its vmcnt wait here) so the
  // stage loads below are the only outstanding VMEM ops -> exact vmcnt ledger.
  asm volatile("" : "+v"(t4.x), "+v"(t4.y), "+v"(t4.z), "+v"(t4.w));

  // Issue all 19 stages. Global src is per-lane (base includes tid*4); LDS
  // dest is wave-uniform; HW writes lane's 16B at dest + lane*16, which is
  // exactly &stage[w][c][lane*4] — matching the read below.
#pragma unroll
  for (int c = 0; c < C; c++) {
    __builtin_amdgcn_global_load_lds(
        (const __attribute__((address_space(1))) unsigned int*)(base + c * HW),
        (__attribute__((address_space(3))) unsigned int*)&stage[w][c][0],
        16, 0, 0);
  }

  float s0 = 0.f, s1 = 0.f, s2 = 0.f, s3 = 0.f;
  float e0 = 0.f, e1 = 0.f, e2 = 0.f, e3 = 0.f;

#define CONSUME(c, vm)                                                       \
  {                                                                          \
    asm volatile("s_waitcnt vmcnt(" #vm ")" ::: "memory");                   \
    __builtin_amdgcn_sched_barrier(0);                                       \
    float4 x =                                                               \
        *reinterpret_cast<const float4*>(&stage[w][(c)][lane * 4]);          \
    float ex0 = __expf(x.x), ex1 = __expf(x.y);                              \
    float ex2 = __expf(x.z), ex3 = __expf(x.w);                              \
    s0 += ex0; s1 += ex1; s2 += ex2; s3 += ex3;                              \
    e0 = ((c) == t4.x) ? ex0 : e0; /* c never equals 255 */                  \
    e1 = ((c) == t4.y) ? ex1 : e1;                                           \
    e2 = ((c) == t4.z) ? ex2 : e2;                                           \
    e3 = ((c) == t4.w) ? ex3 : e3;                                           \
  }

  CONSUME(0, 18)  CONSUME(1, 17)  CONSUME(2, 16)  CONSUME(3, 15)
  CONSUME(4, 14)  CONSUME(5, 13)  CONSUME(6, 12)  CONSUME(7, 11)
  CONSUME(8, 10)  CONSUME(9, 9)   CONSUME(10, 8)  CONSUME(11, 7)
  CONSUME(12, 6)  CONSUME(13, 5)  CONSUME(14, 4)  CONSUME(15, 3)
  CONSUME(16, 2)  CONSUME(17, 1)  CONSUME(18, 0)
#undef CONSUME

  bool va0 = t4.x != IGNORE_INDEX, va1 = t4.y != IGNORE_INDEX;
  bool va2 = t4.z != IGNORE_INDEX, va3 = t4.w != IGNORE_INDEX;
  float mp0 = va0 ? e0 * __frcp_rn(s0) : 1.0f;
  float mp1 = va1 ? e1 * __frcp_rn(s1) : 1.0f;
  float mp2 = va2 ? e2 * __frcp_rn(s2) : 1.0f;
  float mp3 = va3 ? e3 * __frcp_rn(s3) : 1.0f;

  float s = 0.f, cn = 0.f;
  if (mp0 <= THRESH) { s -= __logf(mp0); cn += 1.f; }
  if (mp1 <= THRESH) { s -= __logf(mp1); cn += 1.f; }
  if (mp2 <= THRESH) { s -= __logf(mp2); cn += 1.f; }
  if (mp3 <= THRESH) { s -= __logf(mp3); cn += 1.f; }

  block_reduce2(s, cn);
  if (tid == 0) {
    psumA[blockIdx.x] = s;
    pcntA[blockIdx.x] = cn;
    if (cn > 0.f) atomicAdd(c07, (unsigned)cn);   // cn is an exact small int
  }
}

// ---------------------------------------------------------------------------
// pass1_full (SLOW PATH ONLY, gated): recompute mask_prob from pred, write
// maskprob + top-11-bit LDS histogram (R8's verified kernel). Never runs when
// c07 >= K_SEL.
// ---------------------------------------------------------------------------
__global__ __launch_bounds__(NT, 4) void pass1_full_kernel(
    const float* __restrict__ pred, const int* __restrict__ tgt,
    const unsigned* __restrict__ c07, float* __restrict__ maskprob,
    unsigned* __restrict__ hist0) {
  if (*c07 >= K_SEL) return;
  __shared__ unsigned lh[4 * L0BINS];   // 32 KB
  int tid = threadIdx.x;
  int wid = tid >> 6;
  for (int i = tid; i < 4 * L0BINS; i += NT) lh[i] = 0;
  __syncthreads();

#pragma unroll
  for (int iter = 0; iter < 2; iter++) {
    int p = ((iter * FPBLOCKS + blockIdx.x) * NT + tid) * 4;
    int img = p >> HW_SHIFT;
    int hw = p & (HW - 1);
    const float* base = pred + img * (C * HW) + hw;
    int4 t4 = *reinterpret_cast<const int4*>(tgt + p);

    float s0 = 0.f, s1 = 0.f, s2 = 0.f, s3 = 0.f;
    float e0 = 0.f, e1 = 0.f, e2 = 0.f, e3 = 0.f;
#pragma unroll
    for (int c = 0; c < C; c++) {
      float4 x = *reinterpret_cast<const float4*>(base + c * HW);
      float ex0 = __expf(x.x), ex1 = __expf(x.y);
      float ex2 = __expf(x.z), ex3 = __expf(x.w);
      s0 += ex0; s1 += ex1; s2 += ex2; s3 += ex3;
      e0 = (c == t4.x) ? ex0 : e0;
      e1 = (c == t4.y) ? ex1 : e1;
      e2 = (c == t4.z) ? ex2 : e2;
      e3 = (c == t4.w) ? ex3 : e3;
    }
    bool va0 = t4.x != IGNORE_INDEX, va1 = t4.y != IGNORE_INDEX;
    bool va2 = t4.z != IGNORE_INDEX, va3 = t4.w != IGNORE_INDEX;
    float4 mp;
    mp.x = va0 ? e0 * __frcp_rn(s0) : 1.0f;
    mp.y = va1 ? e1 * __frcp_rn(s1) : 1.0f;
    mp.z = va2 ? e2 * __frcp_rn(s2) : 1.0f;
    mp.w = va3 ? e3 * __frcp_rn(s3) : 1.0f;
    *reinterpret_cast<float4*>(maskprob + p) = mp;

    atomicAdd(&lh[(wid << 11) | (__float_as_uint(mp.x) >> 21)], 1u);
    atomicAdd(&lh[(wid << 11) | (__float_as_uint(mp.y) >> 21)], 1u);
    atomicAdd(&lh[(wid << 11) | (__float_as_uint(mp.z) >> 21)], 1u);
    atomicAdd(&lh[(wid << 11) | (__float_as_uint(mp.w) >> 21)], 1u);
  }
  __syncthreads();
  unsigned rep = blockIdx.x & (NREP - 1);
  for (int i = tid; i < L0BINS; i += NT) {
    unsigned tot = lh[i] + lh[L0BINS + i] + lh[2 * L0BINS + i] +
                   lh[3 * L0BINS + i];
    if (tot) atomicAdd(&hist0[rep * L0BINS + i], tot);
  }
}

// ---------------------------------------------------------------------------
// refine1 (slow path only): scan hist0 (k=K_SEL) -> ctrl[0..1]; histogram
// bits[20:10] of prefix-matching elements into hist1.
// ---------------------------------------------------------------------------
__global__ __launch_bounds__(NT) void refine1_kernel(
    const float* __restrict__ maskprob, const unsigned* __restrict__ c07,
    const unsigned* __restrict__ hist0, unsigned* __restrict__ hist1,
    unsigned* __restrict__ ctrl) {
  if (*c07 >= K_SEL) return;
  __shared__ unsigned lh[L1BINS];
  __shared__ unsigned s_wsum[4];
  __shared__ unsigned s_res[2];
  int tid = threadIdx.x;

  scan_find<L0BINS>(hist0, K_SEL, s_wsum, s_res);
  unsigned pre0 = s_res[0];
  if (tid == 0) { ctrl[0] = pre0; ctrl[1] = s_res[1]; }

  for (int i = tid; i < L1BINS; i += NT) lh[i] = 0;
  __syncthreads();
#pragma unroll
  for (int it = 0; it < 4; it++) {
    int q = (it * RFBLOCKS + blockIdx.x) * NT + tid;
    float4 m = reinterpret_cast<const float4*>(maskprob)[q];
    unsigned bx = __float_as_uint(m.x), by = __float_as_uint(m.y);
    unsigned bz = __float_as_uint(m.z), bw = __float_as_uint(m.w);
    if ((bx >> 21) == pre0) atomicAdd(&lh[(bx >> 10) & (L1BINS - 1)], 1u);
    if ((by >> 21) == pre0) atomicAdd(&lh[(by >> 10) & (L1BINS - 1)], 1u);
    if ((bz >> 21) == pre0) atomicAdd(&lh[(bz >> 10) & (L1BINS - 1)], 1u);
    if ((bw >> 21) == pre0) atomicAdd(&lh[(bw >> 10) & (L1BINS - 1)], 1u);
  }
  __syncthreads();
  unsigned rep = blockIdx.x & (NREP - 1);
  for (int i = tid; i < L1BINS; i += NT)
    if (lh[i]) atomicAdd(&hist1[rep * L1BINS + i], lh[i]);
}

// ---------------------------------------------------------------------------
// refine2 (slow path only): scan hist1 (k=ctrl[1]) -> ctrl[2..3]; histogram
// bits[9:0] into hist2.
// ---------------------------------------------------------------------------
__global__ __launch_bounds__(NT) void refine2_kernel(
    const float* __restrict__ maskprob, const unsigned* __restrict__ c07,
    const unsigned* __restrict__ hist1, unsigned* __restrict__ hist2,
    unsigned* __restrict__ ctrl) {
  if (*c07 >= K_SEL) return;
  __shared__ unsigned lh[L2BINS];
  __shared__ unsigned s_wsum[4];
  __shared__ unsigned s_res[2];
  int tid = threadIdx.x;

  unsigned pre0 = ctrl[0];
  unsigned krem0 = ctrl[1];
  scan_find<L1BINS>(hist1, krem0, s_wsum, s_res);
  unsigned pre1 = (pre0 << 11) | s_res[0];
  if (tid == 0) { ctrl[2] = pre1; ctrl[3] = s_res[1]; }

  for (int i = tid; i < L2BINS; i += NT) lh[i] = 0;
  __syncthreads();
#pragma unroll
  for (int it = 0; it < 4; it++) {
    int q = (it * RFBLOCKS + blockIdx.x) * NT + tid;
    float4 m = reinterpret_cast<const float4*>(maskprob)[q];
    unsigned bx = __float_as_uint(m.x), by = __float_as_uint(m.y);
    unsigned bz = __float_as_uint(m.z), bw = __float_as_uint(m.w);
    if ((bx >> 10) == pre1) atomicAdd(&lh[bx & (L2BINS - 1)], 1u);
    if ((by >> 10) == pre1) atomicAdd(&lh[by & (L2BINS - 1)], 1u);
    if ((bz >> 10) == pre1) atomicAdd(&lh[bz & (L2BINS - 1)], 1u);
    if ((bw >> 10) == pre1) atomicAdd(&lh[bw & (L2BINS - 1)], 1u);
  }
  __syncthreads();
  unsigned rep = blockIdx.x & (NREP - 1);
  for (int i = tid; i < L2BINS; i += NT)
    if (lh[i]) atomicAdd(&hist2[rep * L2BINS + i], lh[i]);
}

// ---------------------------------------------------------------------------
// reduce: FAST PATH (c07 >= K): block 0 combines pass1's partials (thr == 0.7
// exactly) — no bulk data read. SLOW PATH: scan hist2 -> exact kth threshold,
// masked re-read of maskprob+tgt, ticket finalize. Deterministic both ways.
// ---------------------------------------------------------------------------
__global__ __launch_bounds__(NT) void reduce_kernel(
    const float* __restrict__ maskprob, const int* __restrict__ tgt,
    const unsigned* __restrict__ c07, const unsigned* __restrict__ hist2,
    const unsigned* __restrict__ ctrl, const float* __restrict__ psumA,
    const float* __restrict__ pcntA, float* __restrict__ psum,
    float* __restrict__ pcnt, unsigned* __restrict__ ticket,
    float* __restrict__ out) {
  int tid = threadIdx.x;

  if (*c07 >= K_SEL) {
    if (blockIdx.x == 0) {
      float fs = 0.f, fc = 0.f;
      for (int i = tid; i < P1BLOCKS; i += NT) {
        fs += psumA[i];
        fc += pcntA[i];
      }
      block_reduce2(fs, fc);
      if (tid == 0) out[0] = fs / fmaxf(fc, 1.0f);
    }
    return;
  }

  // ---- slow path ----
  __shared__ unsigned s_wsum[4];
  __shared__ unsigned s_res[2];
  __shared__ bool s_last;
  unsigned pre1 = ctrl[2];
  unsigned krem1 = ctrl[3];
  scan_find<L2BINS>(hist2, krem1, s_wsum, s_res);
  float thr = fmaxf(__uint_as_float((pre1 << 10) | s_res[0]), THRESH);

  float s = 0.f, cn = 0.f;
#pragma unroll
  for (int it = 0; it < 4; it++) {
    int q = (it * RBLOCKS + blockIdx.x) * NT + tid;
    float4 m = reinterpret_cast<const float4*>(maskprob)[q];
    int4 t4 = reinterpret_cast<const int4*>(tgt)[q];
    if (t4.x != IGNORE_INDEX && m.x <= thr) { s -= __logf(m.x); cn += 1.f; }
    if (t4.y != IGNORE_INDEX && m.y <= thr) { s -= __logf(m.y); cn += 1.f; }
    if (t4.z != IGNORE_INDEX && m.z <= thr) { s -= __logf(m.z); cn += 1.f; }
    if (t4.w != IGNORE_INDEX && m.w <= thr) { s -= __logf(m.w); cn += 1.f; }
  }
  block_reduce2(s, cn);
  if (tid == 0) {
    psum[blockIdx.x] = s;
    pcnt[blockIdx.x] = cn;
    __threadfence();
    s_last = (atomicAdd(ticket, 1u) == RBLOCKS - 1);
  }
  __syncthreads();
  if (s_last) {
    __threadfence();
    volatile const float* vs = psum;
    volatile const float* vc = pcnt;
    float fs = 0.f, fc = 0.f;
    for (int i = tid; i < RBLOCKS; i += NT) {
      fs += vs[i];
      fc += vc[i];
    }
    block_reduce2(fs, fc);
    if (tid == 0) out[0] = fs / fmaxf(fc, 1.0f);
  }
}

// ---------------------------------------------------------------------------
extern "C" void kernel_launch(void* const* d_in, const int* in_sizes, int n_in,
                              void* d_out, int out_size, void* d_ws,
                              size_t ws_size, hipStream_t stream) {
  const float* pred = (const float*)d_in[0];
  const int* tgt = (const int*)d_in[1];
  float* out = (float*)d_out;

  float* maskprob = (float*)d_ws;                    // 8 MB (slow path only)
  unsigned* hist0 = (unsigned*)(maskprob + N_PIX);   // NREP*2048
  unsigned* hist1 = hist0 + NREP * L0BINS;           // NREP*2048
  unsigned* hist2 = hist1 + NREP * L1BINS;           // NREP*1024
  unsigned* ctrl = hist2 + NREP * L2BINS;            // 16 words
  unsigned* ticket = ctrl + 8;
  unsigned* c07 = ctrl + 9;
  float* psum = (float*)(ctrl + 16);                 // RBLOCKS
  float* pcnt = psum + RBLOCKS;                      // RBLOCKS
  float* psumA = pcnt + RBLOCKS;                     // P1BLOCKS
  float* pcntA = psumA + P1BLOCKS;                   // P1BLOCKS
  size_t zbytes = (char*)(ctrl + 16) - (char*)hist0;

  hipMemsetAsync(hist0, 0, zbytes, stream);
  pass1_kernel<<<P1BLOCKS, NT, 0, stream>>>(pred, tgt, c07, psumA, pcntA);
  pass1_full_kernel<<<FPBLOCKS, NT, 0, stream>>>(pred, tgt, c07, maskprob,
                                                 hist0);
  refine1_kernel<<<RFBLOCKS, NT, 0, stream>>>(maskprob, c07, hist0, hist1, ctrl);
  refine2_kernel<<<RFBLOCKS, NT, 0, stream>>>(maskprob, c07, hist1, hist2, ctrl);
  reduce_kernel<<<RBLOCKS, NT, 0, stream>>>(maskprob, tgt, c07, hist2, ctrl,
                                            psumA, pcntA, psum, pcnt, ticket,
                                            out);
}